// Round 1
// baseline (110.390 us; speedup 1.0000x reference)
//
#include <hip/hip_runtime.h>

#define IN_FEATS 128

// ---------------------------------------------------------------------------
// Phase 1: per-node partial scores.
//   s_src[n] = dot(h[n], W[0:128]);  s_dst[n] = dot(h[n], W[128:256])
// One 64-lane wave per node; lane i handles feature pair (2i, 2i+1).
// ---------------------------------------------------------------------------
__global__ void __launch_bounds__(256)
node_partial_kernel(const float* __restrict__ h,
                    const float* __restrict__ W,
                    float* __restrict__ s_src,
                    float* __restrict__ s_dst,
                    int n_nodes) {
    int gtid = blockIdx.x * blockDim.x + threadIdx.x;
    int node = gtid >> 6;
    int lane = threadIdx.x & 63;
    if (node >= n_nodes) return;

    const float2* hp = (const float2*)(h + (size_t)node * IN_FEATS);
    float2 x  = hp[lane];
    float2 ws = ((const float2*)W)[lane];               // W[0:128]
    float2 wd = ((const float2*)(W + IN_FEATS))[lane];  // W[128:256]

    float ps = x.x * ws.x + x.y * ws.y;
    float pd = x.x * wd.x + x.y * wd.y;

    #pragma unroll
    for (int off = 32; off > 0; off >>= 1) {
        ps += __shfl_down(ps, off, 64);
        pd += __shfl_down(pd, off, 64);
    }
    if (lane == 0) {
        s_src[node] = ps;
        s_dst[node] = pd;
    }
}

// ---------------------------------------------------------------------------
// Phase 2: per-edge gather of the two scalars. 4 edges per thread.
// ---------------------------------------------------------------------------
__global__ void __launch_bounds__(256)
edge_score_kernel(const int* __restrict__ src_idx,
                  const int* __restrict__ dst_idx,
                  const float* __restrict__ s_src,
                  const float* __restrict__ s_dst,
                  const float* __restrict__ bptr,
                  float* __restrict__ out,
                  int n_edges) {
    float bias = bptr[0];
    int i4   = blockIdx.x * blockDim.x + threadIdx.x;  // group of 4 edges
    int base = i4 * 4;
    if (base + 3 < n_edges) {
        int4 s = ((const int4*)src_idx)[i4];
        int4 d = ((const int4*)dst_idx)[i4];
        float4 o;
        o.x = s_src[s.x] + s_dst[d.x] + bias;
        o.y = s_src[s.y] + s_dst[d.y] + bias;
        o.z = s_src[s.z] + s_dst[d.z] + bias;
        o.w = s_src[s.w] + s_dst[d.w] + bias;
        ((float4*)out)[i4] = o;
    } else if (base < n_edges) {
        for (int e = base; e < n_edges; ++e)
            out[e] = s_src[src_idx[e]] + s_dst[dst_idx[e]] + bias;
    }
}

// ---------------------------------------------------------------------------
// Fallback (only if workspace is too small): direct per-edge dot product.
// ---------------------------------------------------------------------------
__global__ void __launch_bounds__(256)
edge_direct_kernel(const float* __restrict__ h,
                   const int* __restrict__ src_idx,
                   const int* __restrict__ dst_idx,
                   const float* __restrict__ W,
                   const float* __restrict__ bptr,
                   float* __restrict__ out,
                   int n_edges) {
    int e = blockIdx.x * blockDim.x + threadIdx.x;
    if (e >= n_edges) return;
    const float4* hs = (const float4*)(h + (size_t)src_idx[e] * IN_FEATS);
    const float4* hd = (const float4*)(h + (size_t)dst_idx[e] * IN_FEATS);
    const float4* Ws = (const float4*)W;
    const float4* Wd = (const float4*)(W + IN_FEATS);
    float acc = bptr[0];
    #pragma unroll
    for (int k = 0; k < IN_FEATS / 4; ++k) {
        float4 a = hs[k], w = Ws[k];
        acc += a.x * w.x + a.y * w.y + a.z * w.z + a.w * w.w;
        float4 c = hd[k], u = Wd[k];
        acc += c.x * u.x + c.y * u.y + c.z * u.z + c.w * u.w;
    }
    out[e] = acc;
}

extern "C" void kernel_launch(void* const* d_in, const int* in_sizes, int n_in,
                              void* d_out, int out_size, void* d_ws, size_t ws_size,
                              hipStream_t stream) {
    const float* h       = (const float*)d_in[0];
    const int*   src_idx = (const int*)d_in[1];
    const int*   dst_idx = (const int*)d_in[2];
    const float* W       = (const float*)d_in[3];
    const float* b       = (const float*)d_in[4];
    float*       out     = (float*)d_out;

    const int n_nodes = in_sizes[0] / IN_FEATS;
    const int n_edges = in_sizes[1];

    const size_t ws_needed = 2 * (size_t)n_nodes * sizeof(float);

    if (ws_size >= ws_needed) {
        float* s_src = (float*)d_ws;
        float* s_dst = s_src + n_nodes;

        // Phase 1: one wave per node, 4 waves per 256-thread block.
        int waves_per_block = 256 / 64;
        int grid1 = (n_nodes + waves_per_block - 1) / waves_per_block;
        node_partial_kernel<<<grid1, 256, 0, stream>>>(h, W, s_src, s_dst, n_nodes);

        // Phase 2: 4 edges per thread.
        int n_groups = (n_edges + 3) / 4;
        int grid2 = (n_groups + 255) / 256;
        edge_score_kernel<<<grid2, 256, 0, stream>>>(src_idx, dst_idx, s_src, s_dst,
                                                     b, out, n_edges);
    } else {
        int grid = (n_edges + 255) / 256;
        edge_direct_kernel<<<grid, 256, 0, stream>>>(h, src_idx, dst_idx, W, b,
                                                     out, n_edges);
    }
}

// Round 2
// 103.258 us; speedup vs baseline: 1.0691x; 1.0691x over previous
//
#include <hip/hip_runtime.h>

#define IN_FEATS 128

// ---------------------------------------------------------------------------
// Phase 1: per-node partial scores.
//   s_src[n] = dot(h[n], W[0:128]) + bias;  s_dst[n] = dot(h[n], W[128:256])
// Two nodes per 64-lane wave: each 32-lane half loads one 512 B row via
// float4 (32 x 16 B), reduces with a 5-level __shfl_xor butterfly (masks <= 16
// never cross the 32-lane half boundary).
// ---------------------------------------------------------------------------
__global__ void __launch_bounds__(256)
node_partial_kernel(const float* __restrict__ h,
                    const float* __restrict__ W,
                    const float* __restrict__ bptr,
                    float* __restrict__ s_src,
                    float* __restrict__ s_dst,
                    int n_nodes) {
    int tid    = threadIdx.x;
    int half   = tid >> 5;        // which 32-lane half-wave within the block (0..7)
    int lane32 = tid & 31;
    int node   = blockIdx.x * 8 + half;
    if (node >= n_nodes) return;  // uniform per 32-lane half

    const float4* hp = (const float4*)(h + (size_t)node * IN_FEATS);
    float4 x  = hp[lane32];
    float4 ws = ((const float4*)W)[lane32];               // W[0:128]
    float4 wd = ((const float4*)(W + IN_FEATS))[lane32];  // W[128:256]

    float ps = x.x * ws.x + x.y * ws.y + x.z * ws.z + x.w * ws.w;
    float pd = x.x * wd.x + x.y * wd.y + x.z * wd.z + x.w * wd.w;

    #pragma unroll
    for (int m = 16; m > 0; m >>= 1) {
        ps += __shfl_xor(ps, m, 64);
        pd += __shfl_xor(pd, m, 64);
    }
    if (lane32 == 0) {
        s_src[node] = ps + bptr[0];  // fold bias here, once per edge later
        s_dst[node] = pd;
    }
}

// ---------------------------------------------------------------------------
// Phase 2: per-edge gather of the two scalars. 4 edges per thread.
// ---------------------------------------------------------------------------
__global__ void __launch_bounds__(256)
edge_score_kernel(const int* __restrict__ src_idx,
                  const int* __restrict__ dst_idx,
                  const float* __restrict__ s_src,
                  const float* __restrict__ s_dst,
                  float* __restrict__ out,
                  int n_edges) {
    int i4   = blockIdx.x * blockDim.x + threadIdx.x;  // group of 4 edges
    int base = i4 * 4;
    if (base + 3 < n_edges) {
        int4 s = ((const int4*)src_idx)[i4];
        int4 d = ((const int4*)dst_idx)[i4];
        float4 o;
        o.x = s_src[s.x] + s_dst[d.x];
        o.y = s_src[s.y] + s_dst[d.y];
        o.z = s_src[s.z] + s_dst[d.z];
        o.w = s_src[s.w] + s_dst[d.w];
        ((float4*)out)[i4] = o;
    } else if (base < n_edges) {
        for (int e = base; e < n_edges; ++e)
            out[e] = s_src[src_idx[e]] + s_dst[dst_idx[e]];
    }
}

// ---------------------------------------------------------------------------
// Fallback (only if workspace is too small): direct per-edge dot product.
// ---------------------------------------------------------------------------
__global__ void __launch_bounds__(256)
edge_direct_kernel(const float* __restrict__ h,
                   const int* __restrict__ src_idx,
                   const int* __restrict__ dst_idx,
                   const float* __restrict__ W,
                   const float* __restrict__ bptr,
                   float* __restrict__ out,
                   int n_edges) {
    int e = blockIdx.x * blockDim.x + threadIdx.x;
    if (e >= n_edges) return;
    const float4* hs = (const float4*)(h + (size_t)src_idx[e] * IN_FEATS);
    const float4* hd = (const float4*)(h + (size_t)dst_idx[e] * IN_FEATS);
    const float4* Ws = (const float4*)W;
    const float4* Wd = (const float4*)(W + IN_FEATS);
    float acc = bptr[0];
    #pragma unroll
    for (int k = 0; k < IN_FEATS / 4; ++k) {
        float4 a = hs[k], w = Ws[k];
        acc += a.x * w.x + a.y * w.y + a.z * w.z + a.w * w.w;
        float4 c = hd[k], u = Wd[k];
        acc += c.x * u.x + c.y * u.y + c.z * u.z + c.w * u.w;
    }
    out[e] = acc;
}

extern "C" void kernel_launch(void* const* d_in, const int* in_sizes, int n_in,
                              void* d_out, int out_size, void* d_ws, size_t ws_size,
                              hipStream_t stream) {
    const float* h       = (const float*)d_in[0];
    const int*   src_idx = (const int*)d_in[1];
    const int*   dst_idx = (const int*)d_in[2];
    const float* W       = (const float*)d_in[3];
    const float* b       = (const float*)d_in[4];
    float*       out     = (float*)d_out;

    const int n_nodes = in_sizes[0] / IN_FEATS;
    const int n_edges = in_sizes[1];

    const size_t ws_needed = 2 * (size_t)n_nodes * sizeof(float);

    if (ws_size >= ws_needed) {
        float* s_src = (float*)d_ws;
        float* s_dst = s_src + n_nodes;

        // Phase 1: 2 nodes per wave -> 8 nodes per 256-thread block.
        int grid1 = (n_nodes + 7) / 8;
        node_partial_kernel<<<grid1, 256, 0, stream>>>(h, W, b, s_src, s_dst,
                                                       n_nodes);

        // Phase 2: 4 edges per thread.
        int n_groups = (n_edges + 3) / 4;
        int grid2 = (n_groups + 255) / 256;
        edge_score_kernel<<<grid2, 256, 0, stream>>>(src_idx, dst_idx, s_src,
                                                     s_dst, out, n_edges);
    } else {
        int grid = (n_edges + 255) / 256;
        edge_direct_kernel<<<grid, 256, 0, stream>>>(h, src_idx, dst_idx, W, b,
                                                     out, n_edges);
    }
}

// Round 3
// 101.800 us; speedup vs baseline: 1.0844x; 1.0143x over previous
//
#include <hip/hip_runtime.h>

#define IN_FEATS 128

// ---------------------------------------------------------------------------
// Phase 1: per-node partial scores.
//   s_src[n] = dot(h[n], W[0:128]) + bias;  s_dst[n] = dot(h[n], W[128:256])
// Four nodes per 64-lane wave: each 16-lane group owns one 512 B row, each
// lane loads 2 x float4 (32 B) of it, then a 4-level __shfl_xor butterfly
// (masks <= 8 stay within the 16-lane group) reduces the dot products.
// ---------------------------------------------------------------------------
__global__ void __launch_bounds__(256)
node_partial_kernel(const float* __restrict__ h,
                    const float* __restrict__ W,
                    const float* __restrict__ bptr,
                    float* __restrict__ s_src,
                    float* __restrict__ s_dst,
                    int n_nodes) {
    int tid  = threadIdx.x;
    int grp  = tid >> 4;         // 16-lane group within block (0..15)
    int l16  = tid & 15;
    int node = blockIdx.x * 16 + grp;
    if (node >= n_nodes) return; // uniform per 16-lane group

    const float4* hp = (const float4*)(h + (size_t)node * IN_FEATS);
    const float4* Wsরp = (const float4*)W;
    const float4* Wdp = (const float4*)(W + IN_FEATS);

    float4 x0  = hp[l16];
    float4 x1  = hp[l16 + 16];
    float4 ws0 = Wsরp[l16];
    float4 ws1 = Wsরp[l16 + 16];
    float4 wd0 = Wdp[l16];
    float4 wd1 = Wdp[l16 + 16];

    float ps = x0.x * ws0.x + x0.y * ws0.y + x0.z * ws0.z + x0.w * ws0.w
             + x1.x * ws1.x + x1.y * ws1.y + x1.z * ws1.z + x1.w * ws1.w;
    float pd = x0.x * wd0.x + x0.y * wd0.y + x0.z * wd0.z + x0.w * wd0.w
             + x1.x * wd1.x + x1.y * wd1.y + x1.z * wd1.z + x1.w * wd1.w;

    #pragma unroll
    for (int m = 8; m > 0; m >>= 1) {
        ps += __shfl_xor(ps, m, 64);
        pd += __shfl_xor(pd, m, 64);
    }
    if (l16 == 0) {
        s_src[node] = ps + bptr[0];  // bias folded here, applied once per edge
        s_dst[node] = pd;
    }
}

// ---------------------------------------------------------------------------
// Phase 2: per-edge gather of the two scalars. 8 edges per thread.
// ---------------------------------------------------------------------------
__global__ void __launch_bounds__(256)
edge_score_kernel(const int* __restrict__ src_idx,
                  const int* __restrict__ dst_idx,
                  const float* __restrict__ s_src,
                  const float* __restrict__ s_dst,
                  float* __restrict__ out,
                  int n_edges) {
    int i8   = blockIdx.x * blockDim.x + threadIdx.x;  // group of 8 edges
    int base = i8 * 8;
    if (base + 7 < n_edges) {
        int4 s0 = ((const int4*)src_idx)[i8 * 2];
        int4 s1 = ((const int4*)src_idx)[i8 * 2 + 1];
        int4 d0 = ((const int4*)dst_idx)[i8 * 2];
        int4 d1 = ((const int4*)dst_idx)[i8 * 2 + 1];
        float4 o0, o1;
        o0.x = s_src[s0.x] + s_dst[d0.x];
        o0.y = s_src[s0.y] + s_dst[d0.y];
        o0.z = s_src[s0.z] + s_dst[d0.z];
        o0.w = s_src[s0.w] + s_dst[d0.w];
        o1.x = s_src[s1.x] + s_dst[d1.x];
        o1.y = s_src[s1.y] + s_dst[d1.y];
        o1.z = s_src[s1.z] + s_dst[d1.z];
        o1.w = s_src[s1.w] + s_dst[d1.w];
        ((float4*)out)[i8 * 2]     = o0;
        ((float4*)out)[i8 * 2 + 1] = o1;
    } else if (base < n_edges) {
        for (int e = base; e < n_edges; ++e)
            out[e] = s_src[src_idx[e]] + s_dst[dst_idx[e]];
    }
}

// ---------------------------------------------------------------------------
// Fallback (only if workspace is too small): direct per-edge dot product.
// ---------------------------------------------------------------------------
__global__ void __launch_bounds__(256)
edge_direct_kernel(const float* __restrict__ h,
                   const int* __restrict__ src_idx,
                   const int* __restrict__ dst_idx,
                   const float* __restrict__ W,
                   const float* __restrict__ bptr,
                   float* __restrict__ out,
                   int n_edges) {
    int e = blockIdx.x * blockDim.x + threadIdx.x;
    if (e >= n_edges) return;
    const float4* hs = (const float4*)(h + (size_t)src_idx[e] * IN_FEATS);
    const float4* hd = (const float4*)(h + (size_t)dst_idx[e] * IN_FEATS);
    const float4* Ws = (const float4*)W;
    const float4* Wd = (const float4*)(W + IN_FEATS);
    float acc = bptr[0];
    #pragma unroll
    for (int k = 0; k < IN_FEATS / 4; ++k) {
        float4 a = hs[k], w = Ws[k];
        acc += a.x * w.x + a.y * w.y + a.z * w.z + a.w * w.w;
        float4 c = hd[k], u = Wd[k];
        acc += c.x * u.x + c.y * u.y + c.z * u.z + c.w * u.w;
    }
    out[e] = acc;
}

extern "C" void kernel_launch(void* const* d_in, const int* in_sizes, int n_in,
                              void* d_out, int out_size, void* d_ws, size_t ws_size,
                              hipStream_t stream) {
    const float* h       = (const float*)d_in[0];
    const int*   src_idx = (const int*)d_in[1];
    const int*   dst_idx = (const int*)d_in[2];
    const float* W       = (const float*)d_in[3];
    const float* b       = (const float*)d_in[4];
    float*       out     = (float*)d_out;

    const int n_nodes = in_sizes[0] / IN_FEATS;
    const int n_edges = in_sizes[1];

    const size_t ws_needed = 2 * (size_t)n_nodes * sizeof(float);

    if (ws_size >= ws_needed) {
        float* s_src = (float*)d_ws;
        float* s_dst = s_src + n_nodes;

        // Phase 1: 4 nodes per wave -> 16 nodes per 256-thread block.
        int grid1 = (n_nodes + 15) / 16;
        node_partial_kernel<<<grid1, 256, 0, stream>>>(h, W, b, s_src, s_dst,
                                                       n_nodes);

        // Phase 2: 8 edges per thread.
        int n_groups = (n_edges + 7) / 8;
        int grid2 = (n_groups + 255) / 256;
        edge_score_kernel<<<grid2, 256, 0, stream>>>(src_idx, dst_idx, s_src,
                                                     s_dst, out, n_edges);
    } else {
        int grid = (n_edges + 255) / 256;
        edge_direct_kernel<<<grid, 256, 0, stream>>>(h, src_idx, dst_idx, W, b,
                                                     out, n_edges);
    }
}